// Round 5
// baseline (170.228 us; speedup 1.0000x reference)
//
#include <hip/hip_runtime.h>
#include <stdint.h>

#define B_N   4096
#define D_DIM 1024
#define INF_F 3.4e38f

typedef __bf16 bf16x8 __attribute__((ext_vector_type(8)));
typedef float  floatx4 __attribute__((ext_vector_type(4)));

// ws layout (bytes):
//   [0]      u64   minpack[4096]
//   [32768]  u32   maxbits[4096]
//   [49152]  f32   norms[4096]
//   [65600]  i32   ref_idx[4096]
//   [131072] bf16  xbf[4096*1024]  (8 MB)
#define XBF_OFF 131072

__device__ inline unsigned short f2bf_rne(float f) {
    unsigned u = __float_as_uint(f);
    unsigned r = (u + 0x7FFFu + ((u >> 16) & 1u)) >> 16;
    return (unsigned short)r;
}

// One block per row: cast to bf16, row sum-of-squares, init minpack/maxbits.
__global__ __launch_bounds__(256)
void k_prep(const float* __restrict__ x, unsigned short* __restrict__ xbf,
            float* __restrict__ norms,
            unsigned long long* __restrict__ minpack,
            unsigned int* __restrict__ maxbits) {
    const int row = blockIdx.x;
    const int t   = threadIdx.x;
    float4 v = ((const float4*)x)[row * 256 + t];
    ushort4 o;
    o.x = f2bf_rne(v.x); o.y = f2bf_rne(v.y);
    o.z = f2bf_rne(v.z); o.w = f2bf_rne(v.w);
    ((ushort4*)xbf)[row * 256 + t] = o;
    float s = v.x * v.x + v.y * v.y + v.z * v.z + v.w * v.w;
    #pragma unroll
    for (int off = 32; off; off >>= 1) s += __shfl_down(s, off);
    __shared__ float ws4[4];
    if ((t & 63) == 0) ws4[t >> 6] = s;
    __syncthreads();
    if (t == 0) {
        norms[row]   = ws4[0] + ws4[1] + ws4[2] + ws4[3];
        minpack[row] = 0xFFFFFFFFFFFFFFFFull;
        maxbits[row] = 0u;
    }
}

// Barrier-free MFMA Gram pass: fragments loaded DIRECTLY global->registers.
// Per lane, an A/B fragment (16x16x32 layout: row = lane&15, k = (lane>>4)*8+j)
// is 16 contiguous bytes; the 4 q4-lanes of a row cover one full 64B line.
// Register ping-pong pipeline, BK=32 per stage; no LDS staging, no K-loop
// __syncthreads -> compiler schedules fine-grained vmcnt waits.
__global__ __launch_bounds__(256, 2)
void k_pass1_reg(const unsigned short* __restrict__ xbf,
                 const float* __restrict__ norms,
                 unsigned long long* __restrict__ minpack,
                 unsigned int* __restrict__ maxbits) {
    // linear block id -> (ti, tj), tj <= ti
    int bid = blockIdx.x;
    int ti  = (int)((sqrtf(8.f * bid + 1.f) - 1.f) * 0.5f);
    while ((ti + 1) * (ti + 2) / 2 <= bid) ti++;
    while (ti * (ti + 1) / 2 > bid) ti--;
    int tj  = bid - ti * (ti + 1) / 2;

    __shared__ unsigned long long redMin[128][2];
    __shared__ float redMax[128][2];

    const int t    = threadIdx.x;
    const int w    = t >> 6, lane = t & 63;
    const int wm   = w >> 1, wn = w & 1;          // 64x64 quadrant per wave
    const int q4   = lane >> 4, c15 = lane & 15;
    const int i0   = ti * 128, j0 = tj * 128;

    // per-lane fragment pointers (advance 64B = 4 bf16x8 elements per k-chunk)
    const bf16x8* pA[4]; const bf16x8* pB[4];
    #pragma unroll
    for (int st = 0; st < 4; st++) {
        pA[st] = (const bf16x8*)(xbf +
                 (size_t)(i0 + wm * 64 + st * 16 + c15) * D_DIM + q4 * 8);
        pB[st] = (const bf16x8*)(xbf +
                 (size_t)(j0 + wn * 64 + st * 16 + c15) * D_DIM + q4 * 8);
    }

    floatx4 acc[4][4];
    #pragma unroll
    for (int m = 0; m < 4; m++)
        #pragma unroll
        for (int n = 0; n < 4; n++)
            acc[m][n] = (floatx4){0.f, 0.f, 0.f, 0.f};

    bf16x8 a0[4], b0[4], a1[4], b1[4];
    #pragma unroll
    for (int st = 0; st < 4; st++) { a0[st] = pA[st][0]; b0[st] = pB[st][0]; }

    for (int it = 0; it < 32; it += 2) {          // K = 1024, 32 chunks of 32
        // prefetch chunk it+1 into buffer 1
        if (it + 1 < 32) {
            #pragma unroll
            for (int st = 0; st < 4; st++) {
                a1[st] = pA[st][(it + 1) * 4];
                b1[st] = pB[st][(it + 1) * 4];
            }
        }
        #pragma unroll
        for (int m = 0; m < 4; m++)
            #pragma unroll
            for (int n = 0; n < 4; n++)
                acc[m][n] = __builtin_amdgcn_mfma_f32_16x16x32_bf16(
                    a0[m], b0[n], acc[m][n], 0, 0, 0);
        // prefetch chunk it+2 into buffer 0
        if (it + 2 < 32) {
            #pragma unroll
            for (int st = 0; st < 4; st++) {
                a0[st] = pA[st][(it + 2) * 4];
                b0[st] = pB[st][(it + 2) * 4];
            }
        }
        #pragma unroll
        for (int m = 0; m < 4; m++)
            #pragma unroll
            for (int n = 0; n < 4; n++)
                acc[m][n] = __builtin_amdgcn_mfma_f32_16x16x32_bf16(
                    a1[m], b1[n], acc[m][n], 0, 0, 0);
    }

    // epilogue: d = sqrt(ni + nj - 2*dot), strictly j < i; row min-pack + max
    float nj[4];
    #pragma unroll
    for (int st = 0; st < 4; st++) nj[st] = norms[j0 + wn * 64 + st * 16 + c15];

    #pragma unroll
    for (int st_m = 0; st_m < 4; st_m++) {
        #pragma unroll
        for (int r = 0; r < 4; r++) {
            int i_loc = wm * 64 + st_m * 16 + q4 * 4 + r;
            int gi    = i0 + i_loc;
            float ni  = norms[gi];
            unsigned long long mp = 0xFFFFFFFFFFFFFFFFull;
            float mx = -INF_F;
            #pragma unroll
            for (int st_n = 0; st_n < 4; st_n++) {
                int gj = j0 + wn * 64 + st_n * 16 + c15;
                if (gj < gi) {
                    float dot = acc[st_m][st_n][r];
                    float d   = sqrtf(fmaxf(ni + nj[st_n] - 2.f * dot, 0.f));
                    unsigned long long p =
                        ((unsigned long long)__float_as_uint(d) << 32) | (unsigned)gj;
                    if (p < mp) mp = p;
                    mx = fmaxf(mx, d);
                }
            }
            #pragma unroll
            for (int off = 1; off < 16; off <<= 1) {
                unsigned long long op = __shfl_xor(mp, off, 64);
                if (op < mp) mp = op;
                float om = __shfl_xor(mx, off, 64);
                mx = fmaxf(mx, om);
            }
            if (c15 == 0) { redMin[i_loc][wn] = mp; redMax[i_loc][wn] = mx; }
        }
    }
    __syncthreads();
    if (t < 128) {
        unsigned long long mp = redMin[t][0];
        if (redMin[t][1] < mp) mp = redMin[t][1];
        float mx = fmaxf(redMax[t][0], redMax[t][1]);
        if (mp != 0xFFFFFFFFFFFFFFFFull) {
            atomicMin(&minpack[i0 + t], mp);
            atomicMax(&maxbits[i0 + t], __float_as_uint(mx));
        }
    }
}

// Fused: verify all-insert (prefix min/max scan), fast-path outputs, exact
// sequential continuation only if verification failed. One block, 1024 threads.
__global__ __launch_bounds__(1024)
void k_tail(const unsigned long long* __restrict__ minpack,
            const unsigned int* __restrict__ maxbits,
            const float* __restrict__ x, const float* __restrict__ norms,
            const int* __restrict__ labels, int* __restrict__ ref_idx,
            float* __restrict__ out) {
    const int t = threadIdx.x;
    float m[4], M[4];
    #pragma unroll
    for (int q = 0; q < 4; q++) {
        int i = t * 4 + q;
        unsigned long long p = minpack[i];
        float dmin = (p == 0xFFFFFFFFFFFFFFFFull)
                       ? INF_F : __uint_as_float((unsigned)(p >> 32));
        m[q] = (i == 0) ? INF_F : dmin;
        M[q] = (i == 0) ? -INF_F : __uint_as_float(maxbits[i]);
    }
    float pmin[4], pmax[4];
    pmin[0] = m[0]; pmax[0] = M[0];
    #pragma unroll
    for (int q = 1; q < 4; q++) {
        pmin[q] = fminf(pmin[q - 1], m[q]);
        pmax[q] = fmaxf(pmax[q - 1], M[q]);
    }
    __shared__ float smin[1024], smax[1024];
    smin[t] = pmin[3]; smax[t] = pmax[3];
    __syncthreads();
    for (int off = 1; off < 1024; off <<= 1) {
        float a = (t >= off) ? smin[t - off] : INF_F;
        float b = (t >= off) ? smax[t - off] : -INF_F;
        __syncthreads();
        smin[t] = fminf(smin[t], a);
        smax[t] = fmaxf(smax[t], b);
        __syncthreads();
    }
    float exMin = (t > 0) ? smin[t - 1] : INF_F;
    float exMax = (t > 0) ? smax[t - 1] : -INF_F;

    int viol = B_N;
    #pragma unroll
    for (int q = 0; q < 4; q++) {
        int i = t * 4 + q;
        if (i >= 1) {
            float pm = (q == 0) ? exMin : fminf(exMin, pmin[q - 1]);
            float pM = (q == 0) ? exMax : fmaxf(exMax, pmax[q - 1]);
            float R  = (i == 1) ? 1.0f : (pm + pM) / 3.0f;
            if (!(m[q] > R) && i < viol) viol = i;
        }
    }
    __shared__ int sv[1024];
    sv[t] = viol;
    __syncthreads();
    for (int off = 512; off; off >>= 1) {
        if (t < off) sv[t] = min(sv[t], sv[t + off]);
        __syncthreads();
    }
    const int s_star = sv[0];

    for (int i = t; i < s_star; i += 1024) out[i] = (float)labels[i];

    __shared__ float s_state[3];
    __shared__ int s_n;
    if (s_star < B_N && t == (s_star >> 2)) {
        int q = s_star & 3;
        float pm = (q == 0) ? exMin : fminf(exMin, pmin[q - 1]);
        float pM = (q == 0) ? exMax : fmaxf(exMax, pmax[q - 1]);
        float md = fminf(pm, m[q]);
        float Md = fmaxf(pM, M[q]);
        s_state[0] = md; s_state[1] = Md; s_state[2] = (md + Md) / 3.0f;
        s_n = s_star;
        unsigned long long p = minpack[s_star];
        int j = (int)(unsigned)(p & 0xFFFFFFFFu);
        out[s_star] = (float)labels[j];
    }
    if (s_star >= B_N) return;

    for (int s = t; s < s_star; s += 1024) ref_idx[s] = s;
    __syncthreads();

    __shared__ unsigned long long redp[1024];
    __shared__ float redm[1024];
    for (int i = s_star + 1; i < B_N; i++) {
        int n = s_n;
        const float* xi = x + (size_t)i * D_DIM;
        float ni = norms[i];
        unsigned long long mp = 0xFFFFFFFFFFFFFFFFull;
        float mx = -INF_F;
        for (int slot = t; slot < n; slot += 1024) {
            int j = ref_idx[slot];
            const float* xj = x + (size_t)j * D_DIM;
            float dot = 0.f;
            for (int k = 0; k < D_DIM; k++) dot = fmaf(xi[k], xj[k], dot);
            float d = sqrtf(fmaxf(ni + norms[j] - 2.f * dot, 0.f));
            unsigned long long p =
                ((unsigned long long)__float_as_uint(d) << 32) | (unsigned)slot;
            if (p < mp) mp = p;
            mx = fmaxf(mx, d);
        }
        redp[t] = mp; redm[t] = mx;
        __syncthreads();
        for (int off = 512; off; off >>= 1) {
            if (t < off) {
                if (redp[t + off] < redp[t]) redp[t] = redp[t + off];
                redm[t] = fmaxf(redm[t], redm[t + off]);
            }
            __syncthreads();
        }
        if (t == 0) {
            unsigned long long p = redp[0];
            float min_act = __uint_as_float((unsigned)(p >> 32));
            int minslot   = (int)(unsigned)(p & 0xFFFFFFFFu);
            float max_act = redm[0];
            bool insert = (min_act > s_state[2]);
            int pred;
            if (insert) {
                ref_idx[n] = i;
                s_n = n + 1;
                pred = (min_act <= 0.0f) ? labels[ref_idx[minslot]] : labels[i];
            } else {
                pred = labels[ref_idx[minslot]];
            }
            float md = fminf(s_state[0], min_act);
            float Md = fmaxf(s_state[1], max_act);
            s_state[0] = md; s_state[1] = Md; s_state[2] = (md + Md) / 3.0f;
            out[i] = (float)pred;
        }
        __syncthreads();
    }
}

extern "C" void kernel_launch(void* const* d_in, const int* in_sizes, int n_in,
                              void* d_out, int out_size, void* d_ws, size_t ws_size,
                              hipStream_t stream) {
    const float* x      = (const float*)d_in[0];
    const int*   labels = (const int*)d_in[1];
    float*       out    = (float*)d_out;
    char* ws = (char*)d_ws;
    unsigned long long* minpack = (unsigned long long*)ws;
    unsigned int*       maxbits = (unsigned int*)(ws + 32768);
    float*              norms   = (float*)(ws + 49152);
    int*                ref_idx = (int*)(ws + 65600);
    unsigned short*     xbf     = (unsigned short*)(ws + XBF_OFF);

    k_prep<<<B_N, 256, 0, stream>>>(x, xbf, norms, minpack, maxbits);
    const int ntiles  = B_N / 128;                       // 32
    const int nblocks = ntiles * (ntiles + 1) / 2;       // 528
    k_pass1_reg<<<nblocks, 256, 0, stream>>>(xbf, norms, minpack, maxbits);
    k_tail<<<1, 1024, 0, stream>>>(minpack, maxbits, x, norms, labels, ref_idx, out);
}

// Round 6
// 102.252 us; speedup vs baseline: 1.6648x; 1.6648x over previous
//
#include <hip/hip_runtime.h>
#include <stdint.h>

#define B_N   4096
#define D_DIM 1024
#define INF_F 3.4e38f

typedef float floatx4 __attribute__((ext_vector_type(4)));

// ws layout (bytes):
//   [0]      u64   minpack[4096]
//   [32768]  u32   maxbits[4096]
//   [49152]  f32   norms[4096]
//   [65600]  i32   ref_idx[4096]
//   [131072] fp8   xq[4096*1024]  (4 MB)
#define XQ_OFF 131072

// One block per row: cast to fp8 e4m3 (HW RNE), row sum-of-squares (fp32-exact),
// init minpack/maxbits.
__global__ __launch_bounds__(256)
void k_prep(const float* __restrict__ x, unsigned char* __restrict__ xq,
            float* __restrict__ norms,
            unsigned long long* __restrict__ minpack,
            unsigned int* __restrict__ maxbits) {
    const int row = blockIdx.x;
    const int t   = threadIdx.x;
    float4 v = ((const float4*)x)[row * 256 + t];
    int p = __builtin_amdgcn_cvt_pk_fp8_f32(v.x, v.y, 0, false);
    p     = __builtin_amdgcn_cvt_pk_fp8_f32(v.z, v.w, p, true);
    ((int*)xq)[row * 256 + t] = p;
    float s = v.x * v.x + v.y * v.y + v.z * v.z + v.w * v.w;
    #pragma unroll
    for (int off = 32; off; off >>= 1) s += __shfl_down(s, off);
    __shared__ float ws4[4];
    if ((t & 63) == 0) ws4[t >> 6] = s;
    __syncthreads();
    if (t == 0) {
        norms[row]   = ws4[0] + ws4[1] + ws4[2] + ws4[3];
        minpack[row] = 0xFFFFFFFFFFFFFFFFull;
        maxbits[row] = 0u;
    }
}

#define GLDS(g, l)                                                              \
    __builtin_amdgcn_global_load_lds(                                           \
        (__attribute__((address_space(1))) void*)(void*)(g),                    \
        (__attribute__((address_space(3))) void*)(void*)(l), 16, 0, 0)

// fp8 MFMA Gram pass over the lower triangle, fused per-row min/argmin/max.
// R3 structure: single-buffered, BK=128 fp8 (128 B/row), 8 K-iterations.
// LDS row = 8 slots x 16 B, slot swizzle s' = s ^ (row & 7):
//  - staging GLDS keeps the mandatory base+lane*16 contiguity (global side
//    fetches the permuted chunk),
//  - b64 fragment reads land uniformly 4 lanes/bank = wave64-b64 minimum.
__global__ __launch_bounds__(256, 3)
void k_pass1_fp8(const unsigned char* __restrict__ xq,
                 const float* __restrict__ norms,
                 unsigned long long* __restrict__ minpack,
                 unsigned int* __restrict__ maxbits) {
    // linear block id -> (ti, tj), tj <= ti
    int bid = blockIdx.x;
    int ti  = (int)((sqrtf(8.f * bid + 1.f) - 1.f) * 0.5f);
    while ((ti + 1) * (ti + 2) / 2 <= bid) ti++;
    while (ti * (ti + 1) / 2 > bid) ti--;
    int tj  = bid - ti * (ti + 1) / 2;

    __shared__ unsigned char As[16384];      // 128 rows x 128 B (swizzled slots)
    __shared__ unsigned char Bs[16384];
    __shared__ unsigned long long redMin[128][2];
    __shared__ float redMax[128][2];

    const int t    = threadIdx.x;
    const int w    = t >> 6, lane = t & 63;
    const int wm   = w >> 1, wn = w & 1;     // 64x64 quadrant per wave
    const int q4   = lane >> 4, c15 = lane & 15;
    const int i0   = ti * 128, j0 = tj * 128;

    // staging decode: lane -> row-in-instr sr = lane>>3, stored slot s = lane&7,
    // global chunk c = s ^ (sr & 7)
    const int sr = lane >> 3;
    const int sc = (lane & 7) ^ (sr & 7);

    const unsigned char* gA[4]; const unsigned char* gB[4];
    unsigned char* lA[4]; unsigned char* lB[4];
    #pragma unroll
    for (int q = 0; q < 4; q++) {
        int e   = w * 4 + q;                 // staging instruction 0..15
        int row = e * 8 + sr;
        gA[q] = xq + (size_t)(i0 + row) * D_DIM + sc * 16;
        gB[q] = xq + (size_t)(j0 + row) * D_DIM + sc * 16;
        lA[q] = As + e * 1024;               // 1 KB per instruction, wave-uniform
        lB[q] = Bs + e * 1024;
    }

    // fragment offsets: row r (r&7 == c15&7 for all st), byte-in-row
    // b = kk*32 + q4*8 -> slot = kk*2 + (q4>>1), half = q4&1
    const int r7 = c15 & 7;
    int oib[4];
    #pragma unroll
    for (int kk = 0; kk < 4; kk++) {
        int sl  = kk * 2 + (q4 >> 1);
        oib[kk] = (((sl ^ r7) << 4) | ((q4 & 1) << 3));
    }
    int rbA[4], rbB[4];
    #pragma unroll
    for (int st = 0; st < 4; st++) {
        rbA[st] = (wm * 64 + st * 16 + c15) * 128;
        rbB[st] = (wn * 64 + st * 16 + c15) * 128;
    }

    floatx4 acc[4][4];
    #pragma unroll
    for (int m = 0; m < 4; m++)
        #pragma unroll
        for (int n = 0; n < 4; n++)
            acc[m][n] = (floatx4){0.f, 0.f, 0.f, 0.f};

    for (int it = 0; it < 8; it++) {         // K = 1024, BK = 128 fp8
        __syncthreads();
        #pragma unroll
        for (int q = 0; q < 4; q++) {
            GLDS(gA[q], lA[q]);
            GLDS(gB[q], lB[q]);
            gA[q] += 128; gB[q] += 128;
        }
        __syncthreads();
        #pragma unroll
        for (int kk = 0; kk < 4; kk++) {
            long long af[4], bfr[4];
            #pragma unroll
            for (int st = 0; st < 4; st++) {
                af[st]  = *(const long long*)(As + rbA[st] + oib[kk]);
                bfr[st] = *(const long long*)(Bs + rbB[st] + oib[kk]);
            }
            #pragma unroll
            for (int m = 0; m < 4; m++)
                #pragma unroll
                for (int n = 0; n < 4; n++)
                    acc[m][n] = __builtin_amdgcn_mfma_f32_16x16x32_fp8_fp8(
                        af[m], bfr[n], acc[m][n], 0, 0, 0);
        }
    }

    // epilogue: d = sqrt(ni + nj - 2*dot), strictly j < i; row min-pack + max
    float nj[4];
    #pragma unroll
    for (int st = 0; st < 4; st++) nj[st] = norms[j0 + wn * 64 + st * 16 + c15];

    #pragma unroll
    for (int st_m = 0; st_m < 4; st_m++) {
        #pragma unroll
        for (int r = 0; r < 4; r++) {
            int i_loc = wm * 64 + st_m * 16 + q4 * 4 + r;
            int gi    = i0 + i_loc;
            float ni  = norms[gi];
            unsigned long long mp = 0xFFFFFFFFFFFFFFFFull;
            float mx = -INF_F;
            #pragma unroll
            for (int st_n = 0; st_n < 4; st_n++) {
                int gj = j0 + wn * 64 + st_n * 16 + c15;
                if (gj < gi) {
                    float dot = acc[st_m][st_n][r];
                    float d   = sqrtf(fmaxf(ni + nj[st_n] - 2.f * dot, 0.f));
                    unsigned long long p =
                        ((unsigned long long)__float_as_uint(d) << 32) | (unsigned)gj;
                    if (p < mp) mp = p;
                    mx = fmaxf(mx, d);
                }
            }
            #pragma unroll
            for (int off = 1; off < 16; off <<= 1) {
                unsigned long long op = __shfl_xor(mp, off, 64);
                if (op < mp) mp = op;
                float om = __shfl_xor(mx, off, 64);
                mx = fmaxf(mx, om);
            }
            if (c15 == 0) { redMin[i_loc][wn] = mp; redMax[i_loc][wn] = mx; }
        }
    }
    __syncthreads();
    if (t < 128) {
        unsigned long long mp = redMin[t][0];
        if (redMin[t][1] < mp) mp = redMin[t][1];
        float mx = fmaxf(redMax[t][0], redMax[t][1]);
        if (mp != 0xFFFFFFFFFFFFFFFFull) {
            atomicMin(&minpack[i0 + t], mp);
            atomicMax(&maxbits[i0 + t], __float_as_uint(mx));
        }
    }
}

// Fused: verify all-insert (prefix min/max scan), fast-path outputs, exact
// sequential continuation only if verification failed. One block, 1024 threads.
__global__ __launch_bounds__(1024)
void k_tail(const unsigned long long* __restrict__ minpack,
            const unsigned int* __restrict__ maxbits,
            const float* __restrict__ x, const float* __restrict__ norms,
            const int* __restrict__ labels, int* __restrict__ ref_idx,
            float* __restrict__ out) {
    const int t = threadIdx.x;
    float m[4], M[4];
    #pragma unroll
    for (int q = 0; q < 4; q++) {
        int i = t * 4 + q;
        unsigned long long p = minpack[i];
        float dmin = (p == 0xFFFFFFFFFFFFFFFFull)
                       ? INF_F : __uint_as_float((unsigned)(p >> 32));
        m[q] = (i == 0) ? INF_F : dmin;
        M[q] = (i == 0) ? -INF_F : __uint_as_float(maxbits[i]);
    }
    float pmin[4], pmax[4];
    pmin[0] = m[0]; pmax[0] = M[0];
    #pragma unroll
    for (int q = 1; q < 4; q++) {
        pmin[q] = fminf(pmin[q - 1], m[q]);
        pmax[q] = fmaxf(pmax[q - 1], M[q]);
    }
    __shared__ float smin[1024], smax[1024];
    smin[t] = pmin[3]; smax[t] = pmax[3];
    __syncthreads();
    for (int off = 1; off < 1024; off <<= 1) {
        float a = (t >= off) ? smin[t - off] : INF_F;
        float b = (t >= off) ? smax[t - off] : -INF_F;
        __syncthreads();
        smin[t] = fminf(smin[t], a);
        smax[t] = fmaxf(smax[t], b);
        __syncthreads();
    }
    float exMin = (t > 0) ? smin[t - 1] : INF_F;
    float exMax = (t > 0) ? smax[t - 1] : -INF_F;

    int viol = B_N;
    #pragma unroll
    for (int q = 0; q < 4; q++) {
        int i = t * 4 + q;
        if (i >= 1) {
            float pm = (q == 0) ? exMin : fminf(exMin, pmin[q - 1]);
            float pM = (q == 0) ? exMax : fmaxf(exMax, pmax[q - 1]);
            float R  = (i == 1) ? 1.0f : (pm + pM) / 3.0f;
            if (!(m[q] > R) && i < viol) viol = i;
        }
    }
    __shared__ int sv[1024];
    sv[t] = viol;
    __syncthreads();
    for (int off = 512; off; off >>= 1) {
        if (t < off) sv[t] = min(sv[t], sv[t + off]);
        __syncthreads();
    }
    const int s_star = sv[0];

    for (int i = t; i < s_star; i += 1024) out[i] = (float)labels[i];

    __shared__ float s_state[3];
    __shared__ int s_n;
    if (s_star < B_N && t == (s_star >> 2)) {
        int q = s_star & 3;
        float pm = (q == 0) ? exMin : fminf(exMin, pmin[q - 1]);
        float pM = (q == 0) ? exMax : fmaxf(exMax, pmax[q - 1]);
        float md = fminf(pm, m[q]);
        float Md = fmaxf(pM, M[q]);
        s_state[0] = md; s_state[1] = Md; s_state[2] = (md + Md) / 3.0f;
        s_n = s_star;
        unsigned long long p = minpack[s_star];
        int j = (int)(unsigned)(p & 0xFFFFFFFFu);
        out[s_star] = (float)labels[j];
    }
    if (s_star >= B_N) return;

    for (int s = t; s < s_star; s += 1024) ref_idx[s] = s;
    __syncthreads();

    __shared__ unsigned long long redp[1024];
    __shared__ float redm[1024];
    for (int i = s_star + 1; i < B_N; i++) {
        int n = s_n;
        const float* xi = x + (size_t)i * D_DIM;
        float ni = norms[i];
        unsigned long long mp = 0xFFFFFFFFFFFFFFFFull;
        float mx = -INF_F;
        for (int slot = t; slot < n; slot += 1024) {
            int j = ref_idx[slot];
            const float* xj = x + (size_t)j * D_DIM;
            float dot = 0.f;
            for (int k = 0; k < D_DIM; k++) dot = fmaf(xi[k], xj[k], dot);
            float d = sqrtf(fmaxf(ni + norms[j] - 2.f * dot, 0.f));
            unsigned long long p =
                ((unsigned long long)__float_as_uint(d) << 32) | (unsigned)slot;
            if (p < mp) mp = p;
            mx = fmaxf(mx, d);
        }
        redp[t] = mp; redm[t] = mx;
        __syncthreads();
        for (int off = 512; off; off >>= 1) {
            if (t < off) {
                if (redp[t + off] < redp[t]) redp[t] = redp[t + off];
                redm[t] = fmaxf(redm[t], redm[t + off]);
            }
            __syncthreads();
        }
        if (t == 0) {
            unsigned long long p = redp[0];
            float min_act = __uint_as_float((unsigned)(p >> 32));
            int minslot   = (int)(unsigned)(p & 0xFFFFFFFFu);
            float max_act = redm[0];
            bool insert = (min_act > s_state[2]);
            int pred;
            if (insert) {
                ref_idx[n] = i;
                s_n = n + 1;
                pred = (min_act <= 0.0f) ? labels[ref_idx[minslot]] : labels[i];
            } else {
                pred = labels[ref_idx[minslot]];
            }
            float md = fminf(s_state[0], min_act);
            float Md = fmaxf(s_state[1], max_act);
            s_state[0] = md; s_state[1] = Md; s_state[2] = (md + Md) / 3.0f;
            out[i] = (float)pred;
        }
        __syncthreads();
    }
}

extern "C" void kernel_launch(void* const* d_in, const int* in_sizes, int n_in,
                              void* d_out, int out_size, void* d_ws, size_t ws_size,
                              hipStream_t stream) {
    const float* x      = (const float*)d_in[0];
    const int*   labels = (const int*)d_in[1];
    float*       out    = (float*)d_out;
    char* ws = (char*)d_ws;
    unsigned long long* minpack = (unsigned long long*)ws;
    unsigned int*       maxbits = (unsigned int*)(ws + 32768);
    float*              norms   = (float*)(ws + 49152);
    int*                ref_idx = (int*)(ws + 65600);
    unsigned char*      xq      = (unsigned char*)(ws + XQ_OFF);

    k_prep<<<B_N, 256, 0, stream>>>(x, xq, norms, minpack, maxbits);
    const int ntiles  = B_N / 128;                       // 32
    const int nblocks = ntiles * (ntiles + 1) / 2;       // 528
    k_pass1_fp8<<<nblocks, 256, 0, stream>>>(xq, norms, minpack, maxbits);
    k_tail<<<1, 1024, 0, stream>>>(minpack, maxbits, x, norms, labels, ref_idx, out);
}